// Round 4
// baseline (5273.458 us; speedup 1.0000x reference)
//
#include <hip/hip_runtime.h>

#define Bn 2048
#define Hn 1024
#define Ln 96
#define Vn 96

typedef short bf16x8 __attribute__((ext_vector_type(8)));
typedef float f32x4 __attribute__((ext_vector_type(4)));

__device__ __forceinline__ void async16(const void* g, void* l)
{
    __builtin_amdgcn_global_load_lds(
        (const __attribute__((address_space(1))) void*)g,
        (__attribute__((address_space(3))) void*)l, 16, 0, 0);
}

__device__ __forceinline__ unsigned short f2bf(float f)
{
    unsigned u = __float_as_uint(f);
    u += 0x7fff + ((u >> 16) & 1);          // round-to-nearest-even
    return (unsigned short)(u >> 16);
}

__device__ __forceinline__ float bf2f(unsigned short s)
{
    return __uint_as_float(((unsigned)s) << 16);
}

__device__ __forceinline__ float fast_tanh(float x)
{
    float e = __expf(2.0f * x);
    return 1.0f - __fdividef(2.0f, e + 1.0f);
}

// ---------------------------------------------------------------------------
// Fused step kernel, launch index s (0..97). Roles interleaved for balance:
//   bid <  1024, bid&1==0 : L1(t=s-1)  idx = bid>>1
//   bid <  1024, bid&1==1 : L0(t=s)    idx = bid>>1
//   bid >= 1024           : FC(t=s-2)  idx = bid-1024  (+ argmax stats)
// LDS 32 KB total -> 5 blocks/CU, entire 1056-block grid co-resident.
//   A: smem + wave*4096 + buf*2048 (shorts)   16 KB
//   B: smem + 8192 + wave*4096 + buf*2048     16 KB (FC: 3072-short tile, sbuf)
//   reduce f32 aliases smem base after K-loop.
// ---------------------------------------------------------------------------
__global__ __launch_bounds__(128, 2) void fused_step(
    int s,
    const unsigned short* __restrict__ H0rd, unsigned short* __restrict__ H0wr,
    const unsigned short* __restrict__ H1rd, unsigned short* __restrict__ H1wr,
    const unsigned short* __restrict__ W0b,
    const unsigned short* __restrict__ W1ib, const unsigned short* __restrict__ W1hb,
    const unsigned short* __restrict__ fcWb,
    const float* __restrict__ w0ih,
    const float* __restrict__ b0i, const float* __restrict__ b0h,
    const float* __restrict__ b1i, const float* __restrict__ b1h,
    const float* __restrict__ fcb, const float* __restrict__ x,
    float* __restrict__ out,
    float* __restrict__ stats_max, int* __restrict__ stats_arg,
    float* __restrict__ stats_v1)
{
    __shared__ __align__(16) unsigned short smem[16384];   // 32 KB
    const int tid = threadIdx.x;
    const int lane = tid & 63;
    const int wave = tid >> 6;
    const int srow = lane >> 2;        // staging row within 16-row chunk
    const int scol = (lane & 3) * 8;   // staging col (bf16 elems)
    const int lr = lane & 15;
    const int lq = lane >> 4;
    unsigned short* Al = smem + wave * 4096;           // + buf*2048
    unsigned short* Bl = smem + 8192 + wave * 4096;    // + buf*2048
    float* red = (float*)smem;
    const int bid = blockIdx.x;

    if (bid < 1024 && (bid & 1) == 0) {
        // ================= L1(t = s-1), dual GEMM split across waves ======
        if (s < 1 || s > 96) return;
        const int idx = bid >> 1;
        const int bBase = (idx >> 4) * 64;
        const int iBase = (idx & 15) * 64;
        const unsigned short* Ag = wave ? H1rd : H0rd;
        const unsigned short* Bg = wave ? W1hb : W1ib;

        f32x4 acc[4][4];
#pragma unroll
        for (int i = 0; i < 4; ++i)
#pragma unroll
            for (int j = 0; j < 4; ++j) acc[i][j] = (f32x4){0.f, 0.f, 0.f, 0.f};

#pragma unroll
        for (int c = 0; c < 4; ++c) {
            async16(Ag + (size_t)(bBase + c * 16 + srow) * Hn + scol, Al + c * 512);
            async16(Bg + (size_t)(iBase + c * 16 + srow) * Hn + scol, Bl + c * 512);
        }
        int buf = 0;
        for (int it = 0; it < 32; ++it) {
            __syncthreads();
            if (it + 1 < 32) {
                const int kt = (it + 1) * 32;
#pragma unroll
                for (int c = 0; c < 4; ++c) {
                    async16(Ag + (size_t)(bBase + c * 16 + srow) * Hn + kt + scol,
                            Al + (buf ^ 1) * 2048 + c * 512);
                    async16(Bg + (size_t)(iBase + c * 16 + srow) * Hn + kt + scol,
                            Bl + (buf ^ 1) * 2048 + c * 512);
                }
            }
            bf16x8 a[4], b[4];
#pragma unroll
            for (int i = 0; i < 4; ++i) {
                a[i] = *(const bf16x8*)(Al + buf * 2048 + (i * 16 + lr) * 32 + lq * 8);
                b[i] = *(const bf16x8*)(Bl + buf * 2048 + (i * 16 + lr) * 32 + lq * 8);
            }
#pragma unroll
            for (int mt = 0; mt < 4; ++mt)
#pragma unroll
                for (int nt = 0; nt < 4; ++nt)
                    acc[mt][nt] = __builtin_amdgcn_mfma_f32_16x16x32_bf16(
                        a[mt], b[nt], acc[mt][nt], 0, 0, 0);
            buf ^= 1;
        }
        __syncthreads();
        if (wave == 1) {
#pragma unroll
            for (int mt = 0; mt < 4; ++mt)
#pragma unroll
                for (int nt = 0; nt < 4; ++nt)
#pragma unroll
                    for (int r = 0; r < 4; ++r)
                        red[(mt * 16 + lq * 4 + r) * 64 + nt * 16 + lr] = acc[mt][nt][r];
        }
        __syncthreads();
        if (wave == 0) {
#pragma unroll
            for (int nt = 0; nt < 4; ++nt) {
                const int n = iBase + nt * 16 + lr;
                const float bs = b1i[n] + b1h[n];
#pragma unroll
                for (int mt = 0; mt < 4; ++mt)
#pragma unroll
                    for (int r = 0; r < 4; ++r) {
                        const int row = mt * 16 + lq * 4 + r;
                        float v = acc[mt][nt][r] + red[row * 64 + nt * 16 + lr] + bs;
                        H1wr[(size_t)(bBase + row) * Hn + n] = f2bf(fast_tanh(v));
                    }
            }
        }
    } else if (bid < 1024) {
        // ================= L0(t = s), split-K across waves ================
        if (s > 95) return;
        const int idx = bid >> 1;
        const int bBase = (idx >> 4) * 64;
        const int iBase = (idx & 15) * 64;
        const int k0 = wave * 512;
        const unsigned short* Ag = H0rd;
        const unsigned short* Bg = W0b;

        f32x4 acc[4][4];
#pragma unroll
        for (int i = 0; i < 4; ++i)
#pragma unroll
            for (int j = 0; j < 4; ++j) acc[i][j] = (f32x4){0.f, 0.f, 0.f, 0.f};

#pragma unroll
        for (int c = 0; c < 4; ++c) {
            async16(Ag + (size_t)(bBase + c * 16 + srow) * Hn + k0 + scol, Al + c * 512);
            async16(Bg + (size_t)(iBase + c * 16 + srow) * Hn + k0 + scol, Bl + c * 512);
        }
        int buf = 0;
        for (int it = 0; it < 16; ++it) {
            __syncthreads();
            if (it + 1 < 16) {
                const int kt = k0 + (it + 1) * 32;
#pragma unroll
                for (int c = 0; c < 4; ++c) {
                    async16(Ag + (size_t)(bBase + c * 16 + srow) * Hn + kt + scol,
                            Al + (buf ^ 1) * 2048 + c * 512);
                    async16(Bg + (size_t)(iBase + c * 16 + srow) * Hn + kt + scol,
                            Bl + (buf ^ 1) * 2048 + c * 512);
                }
            }
            bf16x8 a[4], b[4];
#pragma unroll
            for (int i = 0; i < 4; ++i) {
                a[i] = *(const bf16x8*)(Al + buf * 2048 + (i * 16 + lr) * 32 + lq * 8);
                b[i] = *(const bf16x8*)(Bl + buf * 2048 + (i * 16 + lr) * 32 + lq * 8);
            }
#pragma unroll
            for (int mt = 0; mt < 4; ++mt)
#pragma unroll
                for (int nt = 0; nt < 4; ++nt)
                    acc[mt][nt] = __builtin_amdgcn_mfma_f32_16x16x32_bf16(
                        a[mt], b[nt], acc[mt][nt], 0, 0, 0);
            buf ^= 1;
        }
        __syncthreads();
        if (wave == 1) {
#pragma unroll
            for (int mt = 0; mt < 4; ++mt)
#pragma unroll
                for (int nt = 0; nt < 4; ++nt)
#pragma unroll
                    for (int r = 0; r < 4; ++r)
                        red[(mt * 16 + lq * 4 + r) * 64 + nt * 16 + lr] = acc[mt][nt][r];
        }
        __syncthreads();
        if (wave == 0) {
#pragma unroll
            for (int nt = 0; nt < 4; ++nt) {
                const int n = iBase + nt * 16 + lr;
                const float wv = w0ih[n];
                const float bs = b0i[n] + b0h[n];
#pragma unroll
                for (int mt = 0; mt < 4; ++mt)
#pragma unroll
                    for (int r = 0; r < 4; ++r) {
                        const int row = mt * 16 + lq * 4 + r;
                        const int bb = bBase + row;
                        const float xv = x[bb * Ln + s];
                        float v = acc[mt][nt][r] + red[row * 64 + nt * 16 + lr] + xv * wv + bs;
                        H0wr[(size_t)bb * Hn + n] = f2bf(fast_tanh(v));
                    }
            }
        }
    } else {
        // ================= FC(t = s-2), split-K, single-buffered ==========
        if (s < 2) return;
        const int t = s - 2;
        const int bBase = (bid - 1024) * 64;
        const int k0 = wave * 512;
        const unsigned short* Ag = H1rd;
        const unsigned short* Bg = fcWb;

        f32x4 acc[4][6];
#pragma unroll
        for (int i = 0; i < 4; ++i)
#pragma unroll
            for (int j = 0; j < 6; ++j) acc[i][j] = (f32x4){0.f, 0.f, 0.f, 0.f};

        for (int it = 0; it < 16; ++it) {
            const int kt = k0 + it * 32;
            __syncthreads();
#pragma unroll
            for (int c = 0; c < 4; ++c)
                async16(Ag + (size_t)(bBase + c * 16 + srow) * Hn + kt + scol, Al + c * 512);
#pragma unroll
            for (int c = 0; c < 6; ++c)
                async16(Bg + (size_t)(c * 16 + srow) * Hn + kt + scol, Bl + c * 512);
            __syncthreads();
            bf16x8 a[4], b[6];
#pragma unroll
            for (int i = 0; i < 4; ++i)
                a[i] = *(const bf16x8*)(Al + (i * 16 + lr) * 32 + lq * 8);
#pragma unroll
            for (int i = 0; i < 6; ++i)
                b[i] = *(const bf16x8*)(Bl + (i * 16 + lr) * 32 + lq * 8);
#pragma unroll
            for (int mt = 0; mt < 4; ++mt)
#pragma unroll
                for (int nt = 0; nt < 6; ++nt)
                    acc[mt][nt] = __builtin_amdgcn_mfma_f32_16x16x32_bf16(
                        a[mt], b[nt], acc[mt][nt], 0, 0, 0);
        }
        __syncthreads();
        if (wave == 1) {
#pragma unroll
            for (int mt = 0; mt < 4; ++mt)
#pragma unroll
                for (int nt = 0; nt < 6; ++nt)
#pragma unroll
                    for (int r = 0; r < 4; ++r)
                        red[(mt * 16 + lq * 4 + r) * 96 + nt * 16 + lr] = acc[mt][nt][r];
        }
        __syncthreads();
        if (wave == 0) {
#pragma unroll
            for (int mt = 0; mt < 4; ++mt)
#pragma unroll
                for (int r = 0; r < 4; ++r) {
                    const int row = mt * 16 + lq * 4 + r;
                    const int bb = bBase + row;
                    const size_t o = (size_t)bb * (Ln * Vn) + (size_t)t * Vn;
                    float ov[6];
#pragma unroll
                    for (int nt = 0; nt < 6; ++nt) {
                        const int v = nt * 16 + lr;
                        ov[nt] = acc[mt][nt][r] + red[row * 96 + v] + fcb[v];
                        out[o + v] = ov[nt];
                    }
                    // per-row argmax stats (raw logits) for the adjust scan
                    float bm = ov[0];
                    int ba = lr;
#pragma unroll
                    for (int nt = 1; nt < 6; ++nt)
                        if (ov[nt] > bm) { bm = ov[nt]; ba = nt * 16 + lr; }
#pragma unroll
                    for (int off = 1; off < 16; off <<= 1) {
                        float om = __shfl_xor(bm, off);
                        int oa = __shfl_xor(ba, off);
                        if (om > bm || (om == bm && oa < ba)) { bm = om; ba = oa; }
                    }
                    float v1 = __shfl_xor(ov[0], 1);  // lane lr=1 holds col 1
                    if (lr == 0) {
                        stats_max[t * Bn + bb] = bm;
                        stats_arg[t * Bn + bb] = ba;
                        stats_v1[t * Bn + bb] = v1;
                    }
                }
        }
    }
}

// ---------------------------------------------------------------------------
// Scalar adjustment scan over precomputed stats. One thread per batch row.
//   cond_u: prev_adj_arg==0 && raw_arg!=1  -> out[b][t][1] += 0.5
//   carried arg = argmax of the adjusted row, derived from (max, arg, v1).
//   t=95: raw_arg==0 -> out[b][95][0] -= 0.5.
// ---------------------------------------------------------------------------
__global__ __launch_bounds__(256) void adjust_scan(
    const float* __restrict__ sm, const int* __restrict__ sa,
    const float* __restrict__ sv1, float* __restrict__ out)
{
    const int b = blockIdx.x * 256 + threadIdx.x;
    if (b >= Bn) return;
    int prev = sa[b];                       // t = 0 raw argmax (no adjustment)
    for (int t = 1; t < Ln; ++t) {
        const int a = sa[t * Bn + b];
        const float m = sm[t * Bn + b];
        int adj = a;
        if (prev == 0 && a != 1) {
            out[(size_t)b * (Ln * Vn) + t * Vn + 1] += 0.5f;
            const float nv = sv1[t * Bn + b] + 0.5f;
            if (nv > m || (nv == m && a > 1)) adj = 1;
        }
        if (t == Ln - 1 && a == 0)
            out[(size_t)b * (Ln * Vn) + t * Vn + 0] -= 0.5f;
        prev = adj;
    }
}

// ---------------------------------------------------------------------------
__global__ void f32_to_bf16(const float* __restrict__ in,
                            unsigned short* __restrict__ out, int n)
{
    int i = blockIdx.x * blockDim.x + threadIdx.x;
    int stride = gridDim.x * blockDim.x;
    for (; i < n; i += stride) out[i] = f2bf(in[i]);
}

__global__ void hidden_out(const unsigned short* __restrict__ h0,
                           const unsigned short* __restrict__ h1,
                           float* __restrict__ out)
{
    int i = blockIdx.x * 256 + threadIdx.x;
    out[i] = bf2f(h0[i]);
    out[(size_t)Bn * Hn + i] = bf2f(h1[i]);
}

// ---------------------------------------------------------------------------
extern "C" void kernel_launch(void* const* d_in, const int* in_sizes, int n_in,
                              void* d_out, int out_size, void* d_ws, size_t ws_size,
                              hipStream_t stream)
{
    const float* x    = (const float*)d_in[0];
    const float* w0ih = (const float*)d_in[1];
    const float* W0   = (const float*)d_in[2];
    const float* b0i  = (const float*)d_in[3];
    const float* b0h  = (const float*)d_in[4];
    const float* W1i  = (const float*)d_in[5];
    const float* W1h  = (const float*)d_in[6];
    const float* b1i  = (const float*)d_in[7];
    const float* b1h  = (const float*)d_in[8];
    const float* fcW  = (const float*)d_in[9];
    const float* fcb  = (const float*)d_in[10];
    float* out = (float*)d_out;

    const size_t HH = (size_t)Hn * Hn;
    const size_t BH = (size_t)Bn * Hn;
    unsigned short* ws = (unsigned short*)d_ws;
    unsigned short* W0b  = ws;
    unsigned short* W1ib = ws + HH;
    unsigned short* W1hb = ws + 2 * HH;
    unsigned short* fcWb = ws + 3 * HH;
    unsigned short* H0[2] = { ws + 4 * HH,          ws + 4 * HH + BH };
    unsigned short* H1[2] = { ws + 4 * HH + 2 * BH, ws + 4 * HH + 3 * BH };
    float* stats_max = (float*)(ws + 4 * HH + 4 * BH);
    int*   stats_arg = (int*)(stats_max + (size_t)Ln * Bn);
    float* stats_v1  = (float*)(stats_arg + (size_t)Ln * Bn);

    hipMemsetAsync(H0[0], 0, BH * sizeof(unsigned short), stream);
    hipMemsetAsync(H1[0], 0, BH * sizeof(unsigned short), stream);

    f32_to_bf16<<<dim3(512), dim3(256), 0, stream>>>(W0,  W0b,  (int)HH);
    f32_to_bf16<<<dim3(512), dim3(256), 0, stream>>>(W1i, W1ib, (int)HH);
    f32_to_bf16<<<dim3(512), dim3(256), 0, stream>>>(W1h, W1hb, (int)HH);
    f32_to_bf16<<<dim3(64),  dim3(256), 0, stream>>>(fcW, fcWb, Vn * Hn);

    // Launch s computes: L0(s) [s<=95], L1(s-1) [s>=1], FC(s-2) [s>=2].
    // h0(t) lives in H0[(t+1)&1]; h1(t) in H1[(t+1)&1].
    for (int s = 0; s <= 97; ++s) {
        fused_step<<<dim3(1056), dim3(128), 0, stream>>>(
            s,
            H0[s & 1], H0[(s + 1) & 1],          // L0 read / write
            H1[(s + 1) & 1], H1[s & 1],          // h1(s-2) read / h1(s-1) write
            W0b, W1ib, W1hb, fcWb,
            w0ih, b0i, b0h, b1i, b1h, fcb, x, out,
            stats_max, stats_arg, stats_v1);
    }

    adjust_scan<<<dim3(8), dim3(256), 0, stream>>>(stats_max, stats_arg, stats_v1, out);

    // final states: h0(95) = H0[0], h1(95) = H1[0]
    hidden_out<<<dim3((int)(BH / 256)), dim3(256), 0, stream>>>(
        H0[0], H1[0], out + (size_t)Bn * Ln * Vn);
}